// Round 15
// baseline (168.762 us; speedup 1.0000x reference)
//
#include <hip/hip_runtime.h>
#include <hip/hip_fp16.h>
#include <math.h>

// Attention_57406532878693: T=2048,B=32,D=1024,H=8,N=128,N2=16
#define T_   2048
#define B_   32
#define D_   1024
#define H_   8
#define N_   128
#define NK   16          // N2 gate width
#define BD4  (B_*D_/4)
#define LOG2E 1.4426950408889634f

typedef __attribute__((ext_vector_type(8))) _Float16 half8;  // fp16x8 frag
typedef __attribute__((ext_vector_type(4))) float f32x4;     // native 4xf32

// convert 8 fp32 (two f32x4) to fp16 fragment (RNE)
__device__ __forceinline__ half8 to_half8(f32x4 a, f32x4 b) {
    half8 r;
    r[0] = (_Float16)a.x; r[1] = (_Float16)a.y;
    r[2] = (_Float16)a.z; r[3] = (_Float16)a.w;
    r[4] = (_Float16)b.x; r[5] = (_Float16)b.y;
    r[6] = (_Float16)b.z; r[7] = (_Float16)b.w;
    return r;
}

__device__ __forceinline__ float tanh_fast(float d) {
    return 1.f - 2.f * __frcp_rn(exp2f(d * (2.f * LOG2E)) + 1.f);
}

// Fused: one block (1024 thr = 16 waves -> 16 waves/CU, same occupancy as
// the 3-kernel pipeline) per (b,h). Phase 1: read own 1MB once -> colsums
// (regs) + P[t][k]=tanh(x.Ww+b) in LDS (fp16, 64KB). Block-local mean->gm.
// Phase 2: e_t from LDS P, then coalesced x re-read weighted accumulate.
// No workspace, no P HBM traffic, no inter-kernel gaps, no k_red.
__global__ __launch_bounds__(1024, 4) void k_fused(
        const float* __restrict__ hyp,  const float* __restrict__ Ww,
        const float* __restrict__ Wb,   const float* __restrict__ Wmw,
        const float* __restrict__ Wmb,  const float* __restrict__ Whw,
        float* __restrict__ out) {
    __shared__ __align__(16) __half Pl[T_ * NK];   // 64 KB P
    __shared__ __align__(16) float scratch[4096];  // 16 KB (red / redc)
    __shared__ float wexp_l[T_];                   //  8 KB e_t
    __shared__ float m_l[N_];
    __shared__ float gw_l[NK];
    __shared__ float zred[16];
    __shared__ float zfin_s;

    const int tid  = threadIdx.x;
    const int lane = tid & 63;
    const int w    = tid >> 6;           // wave 0..15
    const int bh   = blockIdx.x;
    const int b = bh >> 3, h = bh & 7;
    const f32x4* hyp4n = (const f32x4*)hyp;
    const f32x4* Ww4   = (const f32x4*)Ww;
    const int base4 = b * (D_ / 4) + h * (N_ / 4);
    const int kk = lane & 15;            // A-row / gate-k
    const int g  = lane >> 4;            // column group

    // W fragments (fp16) + bias
    half8 wf[4];
#pragma unroll
    for (int ks = 0; ks < 4; ++ks) {
        f32x4 wa  = Ww4[kk * 32 + ks * 8 + g * 2];
        f32x4 wb4 = Ww4[kk * 32 + ks * 8 + g * 2 + 1];
        wf[ks] = to_half8(wa, wb4);
    }
    const float wbr = Wb[kk];

    // ---------------- PHASE 1: colsums + P -> LDS ----------------
    f32x4 cs[8];
#pragma unroll
    for (int m = 0; m < 8; ++m) cs[m] = (f32x4){0.f, 0.f, 0.f, 0.f};

#pragma unroll
    for (int s = 0; s < 8; ++s) {
        const int tb = w * 128 + s * 16;             // step base t
        const int trow = tb + kk;
        const size_t rb = (size_t)trow * BD4 + base4;
        f32x4 xq[8];
        xq[0] = hyp4n[rb + g * 2];      xq[1] = hyp4n[rb + g * 2 + 1];
        xq[2] = hyp4n[rb + 8 + g * 2];  xq[3] = hyp4n[rb + 8 + g * 2 + 1];
        xq[4] = hyp4n[rb + 16 + g * 2]; xq[5] = hyp4n[rb + 16 + g * 2 + 1];
        xq[6] = hyp4n[rb + 24 + g * 2]; xq[7] = hyp4n[rb + 24 + g * 2 + 1];
#pragma unroll
        for (int m = 0; m < 8; ++m) {
            cs[m].x += xq[m].x; cs[m].y += xq[m].y;
            cs[m].z += xq[m].z; cs[m].w += xq[m].w;
        }
        f32x4 acc = {0.f, 0.f, 0.f, 0.f};
#pragma unroll
        for (int ks = 0; ks < 4; ++ks) {
            half8 xf = to_half8(xq[2*ks], xq[2*ks+1]);
            acc = __builtin_amdgcn_mfma_f32_16x16x32_f16(xf, wf[ks], acc, 0, 0, 0);
        }
        const int tl = tb + g * 4;                   // C row -> t = tl + i
#pragma unroll
        for (int i = 0; i < 4; ++i)
            Pl[(tl + i) * NK + kk] = __float2half(tanh_fast(acc[i] + wbr));
    }
    // reduce colsums over kk (lane bits 0-3)
#pragma unroll
    for (int m = 0; m < 8; ++m) {
#pragma unroll
        for (int mask = 1; mask <= 8; mask <<= 1) {
            cs[m].x += __shfl_xor(cs[m].x, mask, 64);
            cs[m].y += __shfl_xor(cs[m].y, mask, 64);
            cs[m].z += __shfl_xor(cs[m].z, mask, 64);
            cs[m].w += __shfl_xor(cs[m].w, mask, 64);
        }
    }
    if (kk == 0) {
#pragma unroll
        for (int m = 0; m < 8; ++m) {
            int nb = 32 * (m >> 1) + 8 * g + 4 * (m & 1);
            scratch[w * N_ + nb + 0] = cs[m].x;
            scratch[w * N_ + nb + 1] = cs[m].y;
            scratch[w * N_ + nb + 2] = cs[m].z;
            scratch[w * N_ + nb + 3] = cs[m].w;
        }
    }
    __syncthreads();
    // ---------------- mean + gm (block-local) ----------------
    if (tid < N_) {
        float s = 0.f;
#pragma unroll
        for (int ww = 0; ww < 16; ++ww) s += scratch[ww * N_ + tid];
        m_l[tid] = s * (1.f / (float)T_);
    }
    __syncthreads();
    if (tid < N_) {
        int k = tid >> 3, g3 = tid & 7;
        float dsum = 0.f;
#pragma unroll
        for (int i = 0; i < 16; ++i) {
            int n = g3 * 16 + i;
            dsum = fmaf(m_l[n], Wmw[k * N_ + n], dsum);
        }
        dsum += __shfl_xor(dsum, 1, 64);
        dsum += __shfl_xor(dsum, 2, 64);
        dsum += __shfl_xor(dsum, 4, 64);
        if (g3 == 0) gw_l[k] = tanhf(dsum + Wmb[k]) * Whw[k];
    }
    __syncthreads();

    // ---------------- PHASE 2a: e_t from LDS P (2 t per thread) ----------
    {
        float zl = 0.f;
#pragma unroll
        for (int r = 0; r < 2; ++r) {
            const int t = r * 1024 + tid;
            const uint4* pv = (const uint4*)&Pl[t * NK];
            union { uint4 u; __half2 hh[4]; } Pa, Pb;
            Pa.u = pv[0]; Pb.u = pv[1];
            float lg = 0.f;
#pragma unroll
            for (int q = 0; q < 4; ++q) {
                float2 f0 = __half22float2(Pa.hh[q]);
                float2 f1 = __half22float2(Pb.hh[q]);
                lg = fmaf(f0.x, gw_l[2*q + 0], lg);
                lg = fmaf(f0.y, gw_l[2*q + 1], lg);
                lg = fmaf(f1.x, gw_l[8 + 2*q + 0], lg);
                lg = fmaf(f1.y, gw_l[8 + 2*q + 1], lg);
            }
            float e = exp2f(lg * LOG2E);   // unshifted: |lg| <= sum|Whw| <= 4
            wexp_l[t] = e;
            zl += e;
        }
        zl += __shfl_xor(zl, 1, 64);  zl += __shfl_xor(zl, 2, 64);
        zl += __shfl_xor(zl, 4, 64);  zl += __shfl_xor(zl, 8, 64);
        zl += __shfl_xor(zl, 16, 64); zl += __shfl_xor(zl, 32, 64);
        if (lane == 0) zred[w] = zl;
    }
    __syncthreads();
    if (tid == 0) {
        float z = 0.f;
#pragma unroll
        for (int i = 0; i < 16; ++i) z += zred[i];
        zfin_s = z;
    }

    // ---------------- PHASE 2b: weighted x accumulate (coalesced) --------
    const int col4 = tid & 31, tg = tid >> 5;        // tg 0..31, 64 t each
    f32x4 c0 = {0.f,0.f,0.f,0.f}, c1 = {0.f,0.f,0.f,0.f};
    const float* we = &wexp_l[tg * 64];
    const size_t rbase = (size_t)(tg * 64) * BD4 + base4 + col4;
#pragma unroll 8
    for (int i = 0; i < 64; i += 2) {
        float w0 = we[i], w1 = we[i + 1];
        f32x4 x0 = hyp4n[rbase + (size_t)i * BD4];
        f32x4 x1 = hyp4n[rbase + (size_t)(i + 1) * BD4];
        c0.x = fmaf(w0, x0.x, c0.x); c0.y = fmaf(w0, x0.y, c0.y);
        c0.z = fmaf(w0, x0.z, c0.z); c0.w = fmaf(w0, x0.w, c0.w);
        c1.x = fmaf(w1, x1.x, c1.x); c1.y = fmaf(w1, x1.y, c1.y);
        c1.z = fmaf(w1, x1.z, c1.z); c1.w = fmaf(w1, x1.w, c1.w);
    }
    c0.x += c1.x; c0.y += c1.y; c0.z += c1.z; c0.w += c1.w;
    __syncthreads();                     // scratch free (mean done), zfin set
    *(f32x4*)&scratch[(tg * 32 + col4) * 4] = c0;
    __syncthreads();
    if (tid < N_) {
        const int c4 = tid >> 2, jj = tid & 3;
        float s = 0.f;
#pragma unroll
        for (int t32 = 0; t32 < 32; ++t32)
            s += scratch[(t32 * 32 + c4) * 4 + jj];
        out[bh * N_ + tid] = s / zfin_s;
    }
}

extern "C" void kernel_launch(void* const* d_in, const int* in_sizes, int n_in,
                              void* d_out, int out_size, void* d_ws, size_t ws_size,
                              hipStream_t stream) {
    const float* hyp = (const float*)d_in[0];
    const float* Ww  = (const float*)d_in[1];
    const float* Wb  = (const float*)d_in[2];
    const float* Wmw = (const float*)d_in[3];
    const float* Wmb = (const float*)d_in[4];
    const float* Whw = (const float*)d_in[5];
    // d_in[6] = Wh_b: unused (softmax shift-invariant)
    float* out = (float*)d_out;

    k_fused<<<dim3(B_ * H_), 1024, 0, stream>>>(hyp, Ww, Wb, Wmw, Wmb, Whw, out);
}

// Round 16
// 105.416 us; speedup vs baseline: 1.6009x; 1.6009x over previous
//
#include <hip/hip_runtime.h>
#include <hip/hip_fp16.h>
#include <math.h>

// Attention_57406532878693: T=2048,B=32,D=1024,H=8,N=128,N2=16
// Best-known structure (round 9, 105.3 us): 3-kernel split-T pipeline.
// k_p: one x pass -> colsums + P=tanh(x.Ww+b) (fp16, LDS-staged flush).
// k_att: second x pass -> gm (folded), logits from P, unshifted exp,
//        weighted accumulate. XCD-matched reverse block order.
// k_red: merge 8 split partials per bh.
#define T_   2048
#define B_   32
#define D_   1024
#define H_   8
#define N_   128
#define NK   16          // N2 gate width
#define TSPL 8           // T-splits per (b,h)
#define TBLK (T_/TSPL)   // 256 t per unit
#define BD4  (B_*D_/4)
#define APS  132         // attp stride per unit (128 c + Z + pad)
#define LOG2E 1.4426950408889634f

typedef __attribute__((ext_vector_type(8))) short short8;   // bf16x8 frag
typedef __attribute__((ext_vector_type(4))) float f32x4;    // C/D frag

// split 8 fp32 (two float4) into truncated bf16 hi + bf16(lo) fragments
__device__ __forceinline__ void split_bf16(float4 a, float4 b,
                                           short8& hi, short8& lo) {
    union { uint32_t u[4]; short8 v; } H, L;
    uint32_t x0 = __float_as_uint(a.x), x1 = __float_as_uint(a.y);
    uint32_t x2 = __float_as_uint(a.z), x3 = __float_as_uint(a.w);
    uint32_t x4 = __float_as_uint(b.x), x5 = __float_as_uint(b.y);
    uint32_t x6 = __float_as_uint(b.z), x7 = __float_as_uint(b.w);
    H.u[0] = (x0 >> 16) | (x1 & 0xFFFF0000u);
    H.u[1] = (x2 >> 16) | (x3 & 0xFFFF0000u);
    H.u[2] = (x4 >> 16) | (x5 & 0xFFFF0000u);
    H.u[3] = (x6 >> 16) | (x7 & 0xFFFF0000u);
    float l0 = a.x - __uint_as_float(x0 & 0xFFFF0000u);
    float l1 = a.y - __uint_as_float(x1 & 0xFFFF0000u);
    float l2 = a.z - __uint_as_float(x2 & 0xFFFF0000u);
    float l3 = a.w - __uint_as_float(x3 & 0xFFFF0000u);
    float l4 = b.x - __uint_as_float(x4 & 0xFFFF0000u);
    float l5 = b.y - __uint_as_float(x5 & 0xFFFF0000u);
    float l6 = b.z - __uint_as_float(x6 & 0xFFFF0000u);
    float l7 = b.w - __uint_as_float(x7 & 0xFFFF0000u);
    L.u[0] = (__float_as_uint(l0) >> 16) | (__float_as_uint(l1) & 0xFFFF0000u);
    L.u[1] = (__float_as_uint(l2) >> 16) | (__float_as_uint(l3) & 0xFFFF0000u);
    L.u[2] = (__float_as_uint(l4) >> 16) | (__float_as_uint(l5) & 0xFFFF0000u);
    L.u[3] = (__float_as_uint(l6) >> 16) | (__float_as_uint(l7) & 0xFFFF0000u);
    hi = H.v; lo = L.v;
}

__device__ __forceinline__ float tanh_fast(float d) {
    return 1.f - 2.f * __frcp_rn(exp2f(d * (2.f * LOG2E)) + 1.f);
}

// load 8 float4 of x for one 16-t step (lane's t-row = t0+step*64+w*16+kk)
#define LOADX(dst, step_) { \
    const int trow_ = t0 + (step_) * 64 + w * 16 + kk; \
    const size_t rb_ = (size_t)trow_ * BD4 + base4; \
    (dst)[0] = hyp4[rb_ + g * 2];      (dst)[1] = hyp4[rb_ + g * 2 + 1]; \
    (dst)[2] = hyp4[rb_ + 8 + g * 2];  (dst)[3] = hyp4[rb_ + 8 + g * 2 + 1]; \
    (dst)[4] = hyp4[rb_ + 16 + g * 2]; (dst)[5] = hyp4[rb_ + 16 + g * 2 + 1]; \
    (dst)[6] = hyp4[rb_ + 24 + g * 2]; (dst)[7] = hyp4[rb_ + 24 + g * 2 + 1]; }

// K1: one block per (bh,spl). One x read: colsums -> part[blk][128],
// P[t][k] = tanh(x.Ww + b) staged in LDS, flushed coalesced to Pbuf (fp16).
__global__ __launch_bounds__(256, 4) void k_p(const float* __restrict__ hyp,
                                              const float* __restrict__ Ww,
                                              const float* __restrict__ Wb,
                                              float* __restrict__ part,
                                              __half* __restrict__ Pbuf) {
    __shared__ float red[4 * N_];
    __shared__ __half Pl[TBLK * NK];     // 8 KB unit P staging
    const int tid  = threadIdx.x;
    const int lane = tid & 63;
    const int w    = tid >> 6;
    const int blk  = blockIdx.x;
    const int bh   = blk >> 3;
    const int spl  = blk & 7;
    const int b = bh >> 3, h = bh & 7;
    const int t0 = spl * TBLK;
    const float4* hyp4 = (const float4*)hyp;
    const float4* Ww4  = (const float4*)Ww;
    const int base4 = b * (D_ / 4) + h * (N_ / 4);
    const int kk = lane & 15;
    const int g  = lane >> 4;

    short8 wh[4], wlo[4];
#pragma unroll
    for (int ks = 0; ks < 4; ++ks) {
        float4 wa  = Ww4[kk * 32 + ks * 8 + g * 2];
        float4 wb4 = Ww4[kk * 32 + ks * 8 + g * 2 + 1];
        split_bf16(wa, wb4, wh[ks], wlo[ks]);
    }
    const float wbr = Wb[kk];

    float4 cs[8];
#pragma unroll
    for (int m = 0; m < 8; ++m) cs[m] = make_float4(0.f, 0.f, 0.f, 0.f);

#pragma unroll
    for (int step = 0; step < 4; ++step) {
        float4 xq[8];
        LOADX(xq, step);
#pragma unroll
        for (int m = 0; m < 8; ++m) {
            cs[m].x += xq[m].x; cs[m].y += xq[m].y;
            cs[m].z += xq[m].z; cs[m].w += xq[m].w;
        }
        f32x4 acc = {0.f, 0.f, 0.f, 0.f};
#pragma unroll
        for (int ks = 0; ks < 4; ++ks) {
            short8 xh, xl;
            split_bf16(xq[2*ks], xq[2*ks+1], xh, xl);
            acc = __builtin_amdgcn_mfma_f32_16x16x32_bf16(xh, wh[ks],  acc, 0, 0, 0);
            acc = __builtin_amdgcn_mfma_f32_16x16x32_bf16(xl, wh[ks],  acc, 0, 0, 0);
            acc = __builtin_amdgcn_mfma_f32_16x16x32_bf16(xh, wlo[ks], acc, 0, 0, 0);
        }
        // stage P[t_local = step*64+w*16+g*4+i][kk] in LDS
        const int tl = step * 64 + w * 16 + g * 4;
#pragma unroll
        for (int i = 0; i < 4; ++i)
            Pl[(tl + i) * NK + kk] = __float2half(tanh_fast(acc[i] + wbr));
    }
    __syncthreads();
    // coalesced flush: 8 KB contiguous (unit is t-major inside bh)
    {
        const uint4* src = (const uint4*)Pl;
        uint4* dst = (uint4*)(Pbuf + ((size_t)bh * T_ + t0) * NK);
        dst[tid]       = src[tid];
        dst[tid + 256] = src[tid + 256];
    }
    // reduce colsums over kk (lane bits 0-3)
#pragma unroll
    for (int m = 0; m < 8; ++m) {
#pragma unroll
        for (int mask = 1; mask <= 8; mask <<= 1) {
            cs[m].x += __shfl_xor(cs[m].x, mask, 64);
            cs[m].y += __shfl_xor(cs[m].y, mask, 64);
            cs[m].z += __shfl_xor(cs[m].z, mask, 64);
            cs[m].w += __shfl_xor(cs[m].w, mask, 64);
        }
    }
    if (kk == 0) {
#pragma unroll
        for (int m = 0; m < 8; ++m) {
            int nb = 32 * (m >> 1) + 8 * g + 4 * (m & 1);
            red[w * N_ + nb + 0] = cs[m].x;
            red[w * N_ + nb + 1] = cs[m].y;
            red[w * N_ + nb + 2] = cs[m].z;
            red[w * N_ + nb + 3] = cs[m].w;
        }
    }
    __syncthreads();
    if (tid < N_)
        part[blk * N_ + tid] = (red[tid] + red[N_ + tid])
                             + (red[2*N_ + tid] + red[3*N_ + tid]);
}

// K2: one block per (bh,spl). XCD-matched reverse order: unit keeps its
// u%8 XCD (matches k_p's residency) and descends temporally per XCD.
// Prologue: mean from part + gm. Hot loop: logit from own fp16 P row
// (16 fma), unshifted exp (|l|<=4), weighted accumulate.
__global__ __launch_bounds__(256, 4) void k_att(const float* __restrict__ hyp,
                                                const float* __restrict__ part,
                                                const float* __restrict__ Wmw,
                                                const float* __restrict__ Wmb,
                                                const float* __restrict__ Whw,
                                                const __half* __restrict__ Pbuf,
                                                float* __restrict__ attp) {
    __shared__ float red[4 * N_];
    __shared__ float zred[4];
    __shared__ float m_l[N_];
    __shared__ float gw_l[NK];
    const int tid  = threadIdx.x;
    const int lane = tid & 63;
    const int w    = tid >> 6;
    const int j    = (int)blockIdx.x;
    const int blk  = (j & 7) + 8 * (255 - (j >> 3));   // XCD-matched reverse
    const int bh   = blk >> 3;
    const int spl  = blk & 7;
    const int b = bh >> 3, h = bh & 7;
    const int t0 = spl * TBLK;
    const float4* hyp4 = (const float4*)hyp;
    const int base4 = b * (D_ / 4) + h * (N_ / 4);
    const int kk = lane & 15;
    const int g  = lane >> 4;

    // mean for this bh
    if (tid < N_) {
        float s = 0.f;
#pragma unroll
        for (int s8 = 0; s8 < TSPL; ++s8) s += part[(bh * TSPL + s8) * N_ + tid];
        m_l[tid] = s * (1.f / (float)T_);
    }
    __syncthreads();
    // gm: gw_l[k] = tanh(m.Wmw_k + Wmb_k) * Whw_k
    if (tid < N_) {
        int k = tid >> 3, g3 = tid & 7;
        float dsum = 0.f;
#pragma unroll
        for (int i = 0; i < 16; ++i) {
            int n = g3 * 16 + i;
            dsum = fmaf(m_l[n], Wmw[k * N_ + n], dsum);
        }
        dsum += __shfl_xor(dsum, 1, 64);
        dsum += __shfl_xor(dsum, 2, 64);
        dsum += __shfl_xor(dsum, 4, 64);
        if (g3 == 0) gw_l[k] = tanhf(dsum + Wmb[k]) * Whw[k];
    }
    __syncthreads();
    float gmv[NK];
#pragma unroll
    for (int jq = 0; jq < NK; ++jq) gmv[jq] = gw_l[jq];

    float4 cacc[8];
#pragma unroll
    for (int m = 0; m < 8; ++m) cacc[m] = make_float4(0.f, 0.f, 0.f, 0.f);
    float zacc = 0.f;

#pragma unroll
    for (int step = 0; step < 4; ++step) {
        const int tr = t0 + step * 64 + w * 16 + kk;
        // own P row: 16 fp16 = 32 B = 2 uint4
        union { uint4 u; __half2 h[8]; } P0, P1;
        const uint4* pv = (const uint4*)(Pbuf + (size_t)(bh * T_ + tr) * NK);
        P0.u = pv[0]; P1.u = pv[1];
        float4 xq[8];
        LOADX(xq, step);
        float lg = 0.f;
#pragma unroll
        for (int q = 0; q < 4; ++q) {
            float2 f0 = __half22float2(P0.h[q]);
            float2 f1 = __half22float2(P1.h[q]);
            lg = fmaf(f0.x, gmv[2*q + 0], lg);
            lg = fmaf(f0.y, gmv[2*q + 1], lg);
            lg = fmaf(f1.x, gmv[8 + 2*q + 0], lg);
            lg = fmaf(f1.y, gmv[8 + 2*q + 1], lg);
        }
        float e = exp2f(lg * LOG2E);     // unshifted: |lg| <= sum|Whw| <= 4
        zacc += e;
#pragma unroll
        for (int m = 0; m < 8; ++m) {
            cacc[m].x = fmaf(e, xq[m].x, cacc[m].x);
            cacc[m].y = fmaf(e, xq[m].y, cacc[m].y);
            cacc[m].z = fmaf(e, xq[m].z, cacc[m].z);
            cacc[m].w = fmaf(e, xq[m].w, cacc[m].w);
        }
    }
    // reduce cacc and z over kk (lane bits 0-3)
#pragma unroll
    for (int m = 0; m < 8; ++m) {
#pragma unroll
        for (int mask = 1; mask <= 8; mask <<= 1) {
            cacc[m].x += __shfl_xor(cacc[m].x, mask, 64);
            cacc[m].y += __shfl_xor(cacc[m].y, mask, 64);
            cacc[m].z += __shfl_xor(cacc[m].z, mask, 64);
            cacc[m].w += __shfl_xor(cacc[m].w, mask, 64);
        }
    }
    float z = zacc;
    z += __shfl_xor(z, 1, 64);
    z += __shfl_xor(z, 2, 64);
    z += __shfl_xor(z, 4, 64);
    z += __shfl_xor(z, 8, 64);
    if (kk == 0) {
#pragma unroll
        for (int m = 0; m < 8; ++m) {
            int nb = 32 * (m >> 1) + 8 * g + 4 * (m & 1);
            red[w * N_ + nb + 0] = cacc[m].x;
            red[w * N_ + nb + 1] = cacc[m].y;
            red[w * N_ + nb + 2] = cacc[m].z;
            red[w * N_ + nb + 3] = cacc[m].w;
        }
    }
    if (lane == 0) zred[w] = z;
    __syncthreads();
    if (tid < N_) {
        attp[(size_t)blk * APS + tid] =
            (red[tid] + red[N_ + tid]) + (red[2*N_ + tid] + red[3*N_ + tid]);
    } else if (tid == N_) {
        attp[(size_t)blk * APS + N_] =
            (zred[0] + zred[1]) + (zred[2] + zred[3]);
    }
}

// K4: merge TSPL split partials per (b,h): c = sum ci / sum Zi
__global__ __launch_bounds__(128) void k_red(const float* __restrict__ attp,
                                             float* __restrict__ out) {
    int bh = blockIdx.x, tid = threadIdx.x;
    float Z = 0.f, c = 0.f;
#pragma unroll
    for (int s = 0; s < TSPL; ++s) {
        const float* pp = &attp[(size_t)(bh * TSPL + s) * APS];
        Z += pp[N_];
        c += pp[tid];
    }
    out[bh * N_ + tid] = c / Z;
}

extern "C" void kernel_launch(void* const* d_in, const int* in_sizes, int n_in,
                              void* d_out, int out_size, void* d_ws, size_t ws_size,
                              hipStream_t stream) {
    const float* hyp = (const float*)d_in[0];
    const float* Ww  = (const float*)d_in[1];
    const float* Wb  = (const float*)d_in[2];
    const float* Wmw = (const float*)d_in[3];
    const float* Wmb = (const float*)d_in[4];
    const float* Whw = (const float*)d_in[5];
    // d_in[6] = Wh_b: unused (softmax shift-invariant)
    float* out  = (float*)d_out;
    float* part = (float*)d_ws;                  // 2048*128 f  = 1 MB
    float* attp = part + 2048 * N_;              // 2048*132 f ~= 1.06 MB
    __half* Pbuf = (__half*)((char*)d_ws + (4 << 20));  // 16 MB fp16 P

    k_p  <<<dim3(B_ * H_ * TSPL), 256, 0, stream>>>(hyp, Ww, Wb, part, Pbuf);
    k_att<<<dim3(B_ * H_ * TSPL), 256, 0, stream>>>(hyp, part, Wmw, Wmb, Whw,
                                                    Pbuf, attp);
    k_red<<<dim3(B_ * H_), 128, 0, stream>>>(attp, out);
}